// Round 7
// baseline (210.036 us; speedup 1.0000x reference)
//
#include <hip/hip_runtime.h>

typedef unsigned short u16;
typedef unsigned int u32;
typedef __bf16 bf16;
typedef bf16 bf16x8 __attribute__((ext_vector_type(8)));
typedef float f32x4 __attribute__((ext_vector_type(4)));
typedef u32 u32x4 __attribute__((ext_vector_type(4)));
typedef u16 u16x4 __attribute__((ext_vector_type(4)));

#define EMBED 1024
#define HEADS 16
#define HS 64
#define BATCH 2
#define SEQ 2048
#define M_TOT (BATCH * SEQ)   // 4096
#define N_QKV (3 * EMBED)     // 3072
#define KDIM  EMBED           // 1024

// softmax scale folded into exp2: (1/sqrt(64)) * log2(e)
#define CSCALE 0.18033688011112042f
// fixed softmax reference: raw-score bound 64 (s sigma=8; P(|s|>64) ~ 0 over 67M)
#define MREF (64.0f * CSCALE)

__device__ __forceinline__ u16 f2bf(float f) {
  u32 u = __builtin_bit_cast(u32, f);
  u32 r = u + 0x7fffu + ((u >> 16) & 1u);
  return (u16)(r >> 16);
}
__device__ __forceinline__ float bf2f(u16 h) {
  return __builtin_bit_cast(float, (u32)h << 16);
}
__device__ __forceinline__ bf16x8 frag16(const u16* p) {
  return __builtin_bit_cast(bf16x8, *(const u32x4*)p);
}
__device__ __forceinline__ bf16x8 frag16u(const u32* p) {
  return __builtin_bit_cast(bf16x8, *(const u32x4*)p);
}
__device__ __forceinline__ float cl(float v) {
  return fminf(fmaxf(v, -3.0e4f), 3.0e4f);
}
// pack two positive f32 -> bf16 pair (round-nearest, no tie adjust)
__device__ __forceinline__ u32 pk2bf(float lo, float hi) {
  const u32 ul = __builtin_bit_cast(u32, lo) + 0x8000u;
  const u32 uh = __builtin_bit_cast(u32, hi) + 0x8000u;
  return (ul >> 16) | (uh & 0xFFFF0000u);
}

// async global->LDS, 16B per lane (m97 pattern). LDS dest must be lane-linear.
typedef __attribute__((address_space(1))) void gvoid;
typedef __attribute__((address_space(3))) void lvoid;
__device__ __forceinline__ void glds16(const u16* g, u16* l) {
  __builtin_amdgcn_global_load_lds((gvoid*)g, (lvoid*)l, 16, 0, 0);
}

// ---- convert f32 -> bf16, vectorized ----
__global__ __launch_bounds__(256) void convert_kernel(
    const float* __restrict__ in, u16* __restrict__ out, int n4) {
  const int i = blockIdx.x * 256 + threadIdx.x;
  if (i < n4) {
    f32x4 v = *(const f32x4*)(in + (size_t)i * 4);
    u16x4 pk;
#pragma unroll
    for (int j = 0; j < 4; j++) pk[j] = f2bf(v[j]);
    *(u16x4*)(out + (size_t)i * 4) = pk;
  }
}

// ---- transpose + convert: in [R][C] f32 -> out [C][R] bf16 ----
__global__ __launch_bounds__(256) void transpose_conv_kernel(
    const float* __restrict__ in, u16* __restrict__ out, int R, int C) {
  __shared__ u16 tile[32][33];
  const int c0 = blockIdx.x * 32;
  const int r0 = blockIdx.y * 32;
  const int tx = threadIdx.x;
  const int ty = threadIdx.y;
#pragma unroll
  for (int i = 0; i < 32; i += 8)
    tile[ty + i][tx] = f2bf(in[(size_t)(r0 + ty + i) * C + c0 + tx]);
  __syncthreads();
#pragma unroll
  for (int i = 0; i < 32; i += 8)
    out[(size_t)(c0 + ty + i) * R + r0 + tx] = tile[tx][ty + i];
}

// ============ GEMM qkv: xb[4096,1024] @ wt_a[3072,1024]^T + bias ============
// Epilogue: k,q chunks -> kq[4096][2048]; v chunk -> vt[(bq*1024+hd)][2048] (V^T)
__global__ __launch_bounds__(256) void gemm_qkv_kernel(
    const u16* __restrict__ A, const u16* __restrict__ wt,
    const u16* __restrict__ bias, u16* __restrict__ kq, u16* __restrict__ vt) {
  __shared__ u16 As[128 * 32];
  __shared__ u16 Bs[128 * 32];
  const int tid = threadIdx.x;
  const int lane = tid & 63;
  const int wave = tid >> 6;
  const int quad = lane >> 4;
  const int l16 = lane & 15;
  const int wr = wave >> 1;
  const int wc = wave & 1;
  const int m0 = blockIdx.y * 128;
  const int n0 = blockIdx.x * 128;

  f32x4 acc[4][4] = {};
  const int grow = tid >> 2;
  const int gcol = (tid & 3) * 8;

  for (int k0 = 0; k0 < KDIM; k0 += 32) {
    __syncthreads();
    glds16(A + (size_t)(m0 + grow) * KDIM + k0 + gcol, As + tid * 8);
    glds16(A + (size_t)(m0 + grow + 64) * KDIM + k0 + gcol, As + 2048 + tid * 8);
    glds16(wt + (size_t)(n0 + grow) * KDIM + k0 + gcol, Bs + tid * 8);
    glds16(wt + (size_t)(n0 + grow + 64) * KDIM + k0 + gcol, Bs + 2048 + tid * 8);
    __syncthreads();

    bf16x8 af[4], bfr[4];
#pragma unroll
    for (int i = 0; i < 4; i++) {
      af[i]  = frag16(As + (wr * 64 + i * 16 + l16) * 32 + quad * 8);
      bfr[i] = frag16(Bs + (wc * 64 + i * 16 + l16) * 32 + quad * 8);
    }
#pragma unroll
    for (int mi = 0; mi < 4; mi++)
#pragma unroll
      for (int ni = 0; ni < 4; ni++)
        acc[mi][ni] = __builtin_amdgcn_mfma_f32_16x16x32_bf16(
            af[mi], bfr[ni], acc[mi][ni], 0, 0, 0);
  }

#pragma unroll
  for (int ni = 0; ni < 4; ni++) {
    const int n = n0 + wc * 64 + ni * 16 + l16;
    const float bv = bf2f(bias[n]);
    if (n < 2 * EMBED) {
#pragma unroll
      for (int mi = 0; mi < 4; mi++)
#pragma unroll
        for (int r = 0; r < 4; r++) {
          const int m = m0 + wr * 64 + mi * 16 + quad * 4 + r;
          kq[(size_t)m * 2048 + n] = f2bf(cl(acc[mi][ni][r] + bv));
        }
    } else {
      const int hd = n - 2 * EMBED;   // h*64+d
#pragma unroll
      for (int mi = 0; mi < 4; mi++) {
        const int mbase = m0 + wr * 64 + mi * 16 + quad * 4;
        const int bqi = mbase >> 11;
        const int t0 = mbase & 2047;
        u16x4 pk;
#pragma unroll
        for (int r = 0; r < 4; r++) pk[r] = f2bf(cl(acc[mi][ni][r] + bv));
        *(u16x4*)(vt + ((size_t)bqi * EMBED + hd) * SEQ + t0) = pk;
      }
    }
  }
}

// ============ GEMM proj: attb[4096,1024] @ wt_p[1024,1024]^T + bias -> f32 ==
// 128x64 tiles: 512 blocks = 2 blocks/CU (m114-style implicit overlap hides
// the glds16 vmcnt-drain that 1 block/CU left exposed). r3: ~ -6 us.
__global__ __launch_bounds__(128) void gemm_proj_kernel(
    const u16* __restrict__ A, const u16* __restrict__ wt,
    const u16* __restrict__ bias, float* __restrict__ out) {
  __shared__ u16 As[128 * 32];
  __shared__ u16 Bs[64 * 32];
  const int tid = threadIdx.x;
  const int lane = tid & 63;
  const int wave = tid >> 6;        // 0..1 = M-half of the tile
  const int quad = lane >> 4;
  const int l16 = lane & 15;
  const int m0 = blockIdx.y * 128;
  const int n0 = blockIdx.x * 64;

  f32x4 acc[4][4] = {};
  const int grow = tid >> 2;        // 0..31
  const int gcol = (tid & 3) * 8;

  for (int k0 = 0; k0 < KDIM; k0 += 32) {
    __syncthreads();
#pragma unroll
    for (int p = 0; p < 4; p++)
      glds16(A + (size_t)(m0 + p * 32 + grow) * KDIM + k0 + gcol,
             As + p * 1024 + tid * 8);
#pragma unroll
    for (int p = 0; p < 2; p++)
      glds16(wt + (size_t)(n0 + p * 32 + grow) * KDIM + k0 + gcol,
             Bs + p * 1024 + tid * 8);
    __syncthreads();

    bf16x8 af[4], bfr[4];
#pragma unroll
    for (int i = 0; i < 4; i++) {
      af[i]  = frag16(As + (wave * 64 + i * 16 + l16) * 32 + quad * 8);
      bfr[i] = frag16(Bs + (i * 16 + l16) * 32 + quad * 8);
    }
#pragma unroll
    for (int mi = 0; mi < 4; mi++)
#pragma unroll
      for (int ni = 0; ni < 4; ni++)
        acc[mi][ni] = __builtin_amdgcn_mfma_f32_16x16x32_bf16(
            af[mi], bfr[ni], acc[mi][ni], 0, 0, 0);
  }

#pragma unroll
  for (int ni = 0; ni < 4; ni++) {
    const int n = n0 + ni * 16 + l16;
    const float bv = bf2f(bias[n]);
#pragma unroll
    for (int mi = 0; mi < 4; mi++)
#pragma unroll
      for (int r = 0; r < 4; r++) {
        const int m = m0 + wave * 64 + mi * 16 + quad * 4 + r;
        out[(size_t)m * EMBED + n] = cl(acc[mi][ni][r] + bv);
      }
  }
}

// ============ flash attention: barrier-free, register-dbuf K prefetch =======
// kq [4096][2048]: k=[0,1024) q=[1024,2048). vt [bq*1024+hd][2048] = V^T.
// Block = (bh, 32 q rows), ONE wave, 2 independent 16-row q-group streams.
// K LDS dbuf REPLACED by register double-buffer (kA/kB) prefetched ONE
// ITERATION AHEAD from global (L2-resident; addressing = r1's, proven
// correct): the ~4800cy iteration latency trivially covers ~400cy L2.
// Deletes every barrier/vmcnt(0) drain, all K staging + LDS reads + their
// lgkm waits from the serial chain. Manual 2x unroll (body(kA,kB) /
// body(kB,kA)) avoids register copies; all indexing static.
// LDS = 4KB (P only, wave-private, XOR-swizzled).
__global__ __launch_bounds__(64) void attn_kernel(
    const u16* __restrict__ kq, const u16* __restrict__ vt,
    u16* __restrict__ att) {
  __shared__ u32 Ps32[2][16 * 32];

  const int tid = threadIdx.x;      // 0..63, one wave
  const int quad = (tid >> 4) & 3;
  const int l16 = tid & 15;

  const int bh = blockIdx.x;             // XCD = bh % 8 (K/V L2-pinned)
  const int qt32 = 63 - (int)blockIdx.y; // heavy tiles first
  const int q0 = qt32 * 32;
  const int bq = bh >> 4;
  const int h = bh & 15;

  // q-group rows: qg = q0 + g*16 + l16
  int qg[2];
  bf16x8 bq0[2], bq1[2];
#pragma unroll
  for (int g = 0; g < 2; g++) {
    qg[g] = q0 + g * 16 + l16;
    const size_t qrow = (size_t)(bq * SEQ + qg[g]) * 2048 + EMBED + h * HS;
    bq0[g] = frag16(kq + qrow + quad * 8);
    bq1[g] = frag16(kq + qrow + 32 + quad * 8);
  }

  const u16* kb = kq + (size_t)bq * SEQ * 2048 + h * HS;     // K rows
  const u16* vb = vt + ((size_t)bq * EMBED + h * HS) * SEQ;  // V^T rows
  const int psw32 = (l16 & 7) << 2;  // P u32-index XOR swizzle (bits 4:2)

  float lsum[2] = {0.0f, 0.0f};
  f32x4 o[2][4] = {};   // O^T C-layout: d = dc*16 + quad*4 + r, q = l16

  const int nkt = (qt32 >> 1) + 1;

  // K register double-buffer; preload tile 0 into kA
  bf16x8 kA[4][2], kB[4][2];
#pragma unroll
  for (int sub = 0; sub < 4; sub++) {
    const u16* kr = kb + (size_t)(sub * 16 + l16) * 2048 + quad * 8;
    kA[sub][0] = frag16(kr);
    kA[sub][1] = frag16(kr + 32);
  }

  auto body = [&](int kt, bf16x8 (&cur)[4][2], bf16x8 (&nxt)[4][2]) {
    const int k0 = kt * 64;
    // prefetch NEXT K tile into nxt (consumed next iteration; latency hidden)
    if (kt + 1 < nkt) {
#pragma unroll
      for (int sub = 0; sub < 4; sub++) {
        const u16* kr = kb + (size_t)(k0 + 64 + sub * 16 + l16) * 2048 + quad * 8;
        nxt[sub][0] = frag16(kr);
        nxt[sub][1] = frag16(kr + 32);
      }
    }

    // S^T = K . Q^T : K frags from registers, shared by both groups
    f32x4 st[2][4] = {};
    __builtin_amdgcn_s_setprio(1);
#pragma unroll
    for (int sub = 0; sub < 4; sub++) {
#pragma unroll
      for (int g = 0; g < 2; g++) {
        st[g][sub] = __builtin_amdgcn_mfma_f32_16x16x32_bf16(
            cur[sub][0], bq0[g], st[g][sub], 0, 0, 0);
        st[g][sub] = __builtin_amdgcn_mfma_f32_16x16x32_bf16(
            cur[sub][1], bq1[g], st[g][sub], 0, 0, 0);
      }
    }
    __builtin_amdgcn_s_setprio(0);

    // V^T fragments direct from global (issued here; softmax covers latency)
    bf16x8 va[2][4];
#pragma unroll
    for (int kc = 0; kc < 2; kc++)
#pragma unroll
      for (int dc = 0; dc < 4; dc++)
        va[kc][dc] = frag16(vb + (size_t)(dc * 16 + l16) * SEQ + k0 + kc * 32 + quad * 8);

    // fixed-reference softmax + P pack, independent per group
    const bool diag = (kt == nkt - 1);
#pragma unroll
    for (int g = 0; g < 2; g++) {
      float p[4][4];
      if (diag) {          // last tile: mask (wave-uniform branch)
#pragma unroll
        for (int sub = 0; sub < 4; sub++)
#pragma unroll
          for (int r = 0; r < 4; r++) {
            const int key = k0 + sub * 16 + quad * 4 + r;
            const float e = __builtin_amdgcn_exp2f(st[g][sub][r] * CSCALE - MREF);
            p[sub][r] = (key <= qg[g]) ? e : 0.0f;
            lsum[g] += p[sub][r];
          }
      } else {             // fully-causal tile: no mask
#pragma unroll
        for (int sub = 0; sub < 4; sub++)
#pragma unroll
          for (int r = 0; r < 4; r++) {
            p[sub][r] = __builtin_amdgcn_exp2f(st[g][sub][r] * CSCALE - MREF);
            lsum[g] += p[sub][r];
          }
      }
      u32* pw = Ps32[g];
#pragma unroll
      for (int sub = 0; sub < 4; sub++)
#pragma unroll
        for (int rp = 0; rp < 2; rp++)
          pw[l16 * 32 + ((sub * 8 + quad * 2 + rp) ^ psw32)] =
              pk2bf(p[sub][2 * rp], p[sub][2 * rp + 1]);
    }

    // O^T += V^T . P^T (compiler inserts lgkm wait for the same-wave P
    // write->read; no barrier needed in a 1-wave block)
#pragma unroll
    for (int g = 0; g < 2; g++) {
      u32* pw = Ps32[g];
#pragma unroll
      for (int kc = 0; kc < 2; kc++) {
        bf16x8 pb = frag16u(pw + l16 * 32 + ((kc * 16 + quad * 4) ^ psw32));
        __builtin_amdgcn_s_setprio(1);
#pragma unroll
        for (int dc = 0; dc < 4; dc++)
          o[g][dc] = __builtin_amdgcn_mfma_f32_16x16x32_bf16(
              va[kc][dc], pb, o[g][dc], 0, 0, 0);
        __builtin_amdgcn_s_setprio(0);
      }
    }
  };

  for (int kt = 0; kt < nkt; kt += 2) {
    body(kt, kA, kB);
    if (kt + 1 < nkt) body(kt + 1, kB, kA);
  }

  // row-sum reduction + epilogue per group
#pragma unroll
  for (int g = 0; g < 2; g++) {
    float ls = lsum[g];
    ls += __shfl_xor(ls, 16);
    ls += __shfl_xor(ls, 32);
    const float inv = 1.0f / ls;
    const size_t obase = (size_t)(bq * SEQ + qg[g]) * EMBED + h * HS;
#pragma unroll
    for (int dc = 0; dc < 4; dc++) {
      u16 sv[4];
#pragma unroll
      for (int r = 0; r < 4; r++) sv[r] = f2bf(cl(o[g][dc][r] * inv));
      *(u32*)(att + obase + dc * 16 + quad * 4) = (u32)sv[0] | ((u32)sv[1] << 16);
      *(u32*)(att + obase + dc * 16 + quad * 4 + 2) = (u32)sv[2] | ((u32)sv[3] << 16);
    }
  }
}

extern "C" void kernel_launch(void* const* d_in, const int* in_sizes, int n_in,
                              void* d_out, int out_size, void* d_ws,
                              size_t ws_size, hipStream_t stream) {
  const float* x       = (const float*)d_in[0];
  const float* W_atten = (const float*)d_in[1];
  const float* b_atten = (const float*)d_in[2];
  const float* W_proj  = (const float*)d_in[3];
  const float* b_proj  = (const float*)d_in[4];

  // workspace (u16 units), total 41.95 MB
  u16* wt_a = (u16*)d_ws;                         // [3072][1024]
  u16* wt_p = wt_a + (size_t)N_QKV * EMBED;       // [1024][1024]
  u16* ba   = wt_p + (size_t)EMBED * EMBED;       // [3072]
  u16* bp   = ba + N_QKV;                         // [1024]
  u16* xb   = bp + EMBED;                         // [4096][1024]
  u16* kq   = xb + (size_t)M_TOT * KDIM;          // [4096][2048]
  u16* vt   = kq + (size_t)M_TOT * 2048;          // [2*1024][2048]
  u16* attb = xb;                                 // alias (xb dead after qkv GEMM)

  convert_kernel<<<(M_TOT * KDIM / 4 + 255) / 256, 256, 0, stream>>>(
      x, xb, M_TOT * KDIM / 4);
  convert_kernel<<<(N_QKV / 4 + 255) / 256, 256, 0, stream>>>(b_atten, ba, N_QKV / 4);
  convert_kernel<<<(EMBED / 4 + 255) / 256, 256, 0, stream>>>(b_proj, bp, EMBED / 4);
  transpose_conv_kernel<<<dim3(N_QKV / 32, EMBED / 32), dim3(32, 8), 0, stream>>>(
      W_atten, wt_a, EMBED, N_QKV);
  transpose_conv_kernel<<<dim3(EMBED / 32, EMBED / 32), dim3(32, 8), 0, stream>>>(
      W_proj, wt_p, EMBED, EMBED);
  gemm_qkv_kernel<<<dim3(N_QKV / 128, M_TOT / 128), 256, 0, stream>>>(
      xb, wt_a, ba, kq, vt);
  attn_kernel<<<dim3(BATCH * HEADS, SEQ / 32), 64, 0, stream>>>(kq, vt, attb);
  gemm_proj_kernel<<<dim3(EMBED / 64, M_TOT / 128), 128, 0, stream>>>(
      attb, wt_p, bp, (float*)d_out);
}

// Round 8
// 191.277 us; speedup vs baseline: 1.0981x; 1.0981x over previous
//
#include <hip/hip_runtime.h>

typedef unsigned short u16;
typedef unsigned int u32;
typedef __bf16 bf16;
typedef bf16 bf16x8 __attribute__((ext_vector_type(8)));
typedef float f32x4 __attribute__((ext_vector_type(4)));
typedef u32 u32x4 __attribute__((ext_vector_type(4)));
typedef u16 u16x4 __attribute__((ext_vector_type(4)));

#define EMBED 1024
#define HEADS 16
#define HS 64
#define BATCH 2
#define SEQ 2048
#define M_TOT (BATCH * SEQ)   // 4096
#define N_QKV (3 * EMBED)     // 3072
#define KDIM  EMBED           // 1024

// softmax scale folded into exp2: (1/sqrt(64)) * log2(e)
#define CSCALE 0.18033688011112042f
// fixed softmax reference: raw-score bound 64 (s sigma=8; P(|s|>64) ~ 0 over 67M)
#define MREF (64.0f * CSCALE)

__device__ __forceinline__ u16 f2bf(float f) {
  u32 u = __builtin_bit_cast(u32, f);
  u32 r = u + 0x7fffu + ((u >> 16) & 1u);
  return (u16)(r >> 16);
}
__device__ __forceinline__ float bf2f(u16 h) {
  return __builtin_bit_cast(float, (u32)h << 16);
}
__device__ __forceinline__ bf16x8 frag16(const u16* p) {
  return __builtin_bit_cast(bf16x8, *(const u32x4*)p);
}
__device__ __forceinline__ bf16x8 frag16u(const u32* p) {
  return __builtin_bit_cast(bf16x8, *(const u32x4*)p);
}
__device__ __forceinline__ float cl(float v) {
  return fminf(fmaxf(v, -3.0e4f), 3.0e4f);
}
// pack two positive f32 -> bf16 pair (round-nearest, no tie adjust)
__device__ __forceinline__ u32 pk2bf(float lo, float hi) {
  const u32 ul = __builtin_bit_cast(u32, lo) + 0x8000u;
  const u32 uh = __builtin_bit_cast(u32, hi) + 0x8000u;
  return (ul >> 16) | (uh & 0xFFFF0000u);
}

// async global->LDS, 16B per lane (m97 pattern). LDS dest must be lane-linear.
typedef __attribute__((address_space(1))) void gvoid;
typedef __attribute__((address_space(3))) void lvoid;
__device__ __forceinline__ void glds16(const u16* g, u16* l) {
  __builtin_amdgcn_global_load_lds((gvoid*)g, (lvoid*)l, 16, 0, 0);
}

// ---- convert f32 -> bf16, vectorized ----
__global__ __launch_bounds__(256) void convert_kernel(
    const float* __restrict__ in, u16* __restrict__ out, int n4) {
  const int i = blockIdx.x * 256 + threadIdx.x;
  if (i < n4) {
    f32x4 v = *(const f32x4*)(in + (size_t)i * 4);
    u16x4 pk;
#pragma unroll
    for (int j = 0; j < 4; j++) pk[j] = f2bf(v[j]);
    *(u16x4*)(out + (size_t)i * 4) = pk;
  }
}

// ---- transpose + convert: in [R][C] f32 -> out [C][R] bf16 ----
__global__ __launch_bounds__(256) void transpose_conv_kernel(
    const float* __restrict__ in, u16* __restrict__ out, int R, int C) {
  __shared__ u16 tile[32][33];
  const int c0 = blockIdx.x * 32;
  const int r0 = blockIdx.y * 32;
  const int tx = threadIdx.x;
  const int ty = threadIdx.y;
#pragma unroll
  for (int i = 0; i < 32; i += 8)
    tile[ty + i][tx] = f2bf(in[(size_t)(r0 + ty + i) * C + c0 + tx]);
  __syncthreads();
#pragma unroll
  for (int i = 0; i < 32; i += 8)
    out[(size_t)(c0 + ty + i) * R + r0 + tx] = tile[tx][ty + i];
}

// ============ GEMM qkv: xb[4096,1024] @ wt_a[3072,1024]^T + bias ============
// Epilogue: k,q chunks -> kq[4096][2048]; v chunk -> vt2 in MFMA-FRAGMENT
// ORDER: vt2[bqh][kt][kc][dc][quad_t*16+l16d][8e] (u16). Bijection of (d,t):
// d = dc*16 + l16d, t = kt*64 + kc*32 + quad_t*8 + e. Store per (mi,ni) is
// 64 lanes x 8B = 512B CONTIGUOUS (8 lines, was 64 scattered lines); attn's
// V-fragment load becomes lane*16B contiguous 1KB.
__global__ __launch_bounds__(256) void gemm_qkv_kernel(
    const u16* __restrict__ A, const u16* __restrict__ wt,
    const u16* __restrict__ bias, u16* __restrict__ kq, u16* __restrict__ vt) {
  __shared__ u16 As[128 * 32];
  __shared__ u16 Bs[128 * 32];
  const int tid = threadIdx.x;
  const int lane = tid & 63;
  const int wave = tid >> 6;
  const int quad = lane >> 4;
  const int l16 = lane & 15;
  const int wr = wave >> 1;
  const int wc = wave & 1;
  const int m0 = blockIdx.y * 128;
  const int n0 = blockIdx.x * 128;

  f32x4 acc[4][4] = {};
  const int grow = tid >> 2;
  const int gcol = (tid & 3) * 8;

  for (int k0 = 0; k0 < KDIM; k0 += 32) {
    __syncthreads();
    glds16(A + (size_t)(m0 + grow) * KDIM + k0 + gcol, As + tid * 8);
    glds16(A + (size_t)(m0 + grow + 64) * KDIM + k0 + gcol, As + 2048 + tid * 8);
    glds16(wt + (size_t)(n0 + grow) * KDIM + k0 + gcol, Bs + tid * 8);
    glds16(wt + (size_t)(n0 + grow + 64) * KDIM + k0 + gcol, Bs + 2048 + tid * 8);
    __syncthreads();

    bf16x8 af[4], bfr[4];
#pragma unroll
    for (int i = 0; i < 4; i++) {
      af[i]  = frag16(As + (wr * 64 + i * 16 + l16) * 32 + quad * 8);
      bfr[i] = frag16(Bs + (wc * 64 + i * 16 + l16) * 32 + quad * 8);
    }
#pragma unroll
    for (int mi = 0; mi < 4; mi++)
#pragma unroll
      for (int ni = 0; ni < 4; ni++)
        acc[mi][ni] = __builtin_amdgcn_mfma_f32_16x16x32_bf16(
            af[mi], bfr[ni], acc[mi][ni], 0, 0, 0);
  }

#pragma unroll
  for (int ni = 0; ni < 4; ni++) {
    const int n = n0 + wc * 64 + ni * 16 + l16;
    const float bv = bf2f(bias[n]);
    if (n < 2 * EMBED) {
#pragma unroll
      for (int mi = 0; mi < 4; mi++)
#pragma unroll
        for (int r = 0; r < 4; r++) {
          const int m = m0 + wr * 64 + mi * 16 + quad * 4 + r;
          kq[(size_t)m * 2048 + n] = f2bf(cl(acc[mi][ni][r] + bv));
        }
    } else {
      const int hd = n - 2 * EMBED;        // h*64 + d, d&15 == l16
      const int h2 = hd >> 6;              // uniform per ni
      const int dc2 = (hd >> 4) & 3;       // uniform per ni
#pragma unroll
      for (int mi = 0; mi < 4; mi++) {
        const int mbase = m0 + wr * 64 + mi * 16 + quad * 4;
        const int bqi = mbase >> 11;
        const int t0 = mbase & 2047;
        const int kt2 = t0 >> 6;
        const int kc2 = (t0 >> 5) & 1;
        const int qt2 = (t0 >> 3) & 3;     // quad_t (varies with quad)
        const int e0 = t0 & 7;             // 0 or 4
        u16x4 pk;
#pragma unroll
        for (int r = 0; r < 4; r++) pk[r] = f2bf(cl(acc[mi][ni][r] + bv));
        const size_t idx =
            ((((size_t)(bqi * 16 + h2) * 32 + kt2) * 2 + kc2) * 4 + dc2) * 512 +
            (qt2 * 16 + l16) * 8 + e0;
        *(u16x4*)(vt + idx) = pk;
      }
    }
  }
}

// ============ GEMM proj: attb[4096,1024] @ wt_p[1024,1024]^T + bias -> f32 ==
// 128x64 tiles: 512 blocks = 2 blocks/CU (m114-style implicit overlap hides
// the glds16 vmcnt-drain that 1 block/CU left exposed). r3: ~ -6 us.
__global__ __launch_bounds__(128) void gemm_proj_kernel(
    const u16* __restrict__ A, const u16* __restrict__ wt,
    const u16* __restrict__ bias, float* __restrict__ out) {
  __shared__ u16 As[128 * 32];
  __shared__ u16 Bs[64 * 32];
  const int tid = threadIdx.x;
  const int lane = tid & 63;
  const int wave = tid >> 6;        // 0..1 = M-half of the tile
  const int quad = lane >> 4;
  const int l16 = lane & 15;
  const int m0 = blockIdx.y * 128;
  const int n0 = blockIdx.x * 64;

  f32x4 acc[4][4] = {};
  const int grow = tid >> 2;        // 0..31
  const int gcol = (tid & 3) * 8;

  for (int k0 = 0; k0 < KDIM; k0 += 32) {
    __syncthreads();
#pragma unroll
    for (int p = 0; p < 4; p++)
      glds16(A + (size_t)(m0 + p * 32 + grow) * KDIM + k0 + gcol,
             As + p * 1024 + tid * 8);
#pragma unroll
    for (int p = 0; p < 2; p++)
      glds16(wt + (size_t)(n0 + p * 32 + grow) * KDIM + k0 + gcol,
             Bs + p * 1024 + tid * 8);
    __syncthreads();

    bf16x8 af[4], bfr[4];
#pragma unroll
    for (int i = 0; i < 4; i++) {
      af[i]  = frag16(As + (wave * 64 + i * 16 + l16) * 32 + quad * 8);
      bfr[i] = frag16(Bs + (i * 16 + l16) * 32 + quad * 8);
    }
#pragma unroll
    for (int mi = 0; mi < 4; mi++)
#pragma unroll
      for (int ni = 0; ni < 4; ni++)
        acc[mi][ni] = __builtin_amdgcn_mfma_f32_16x16x32_bf16(
            af[mi], bfr[ni], acc[mi][ni], 0, 0, 0);
  }

#pragma unroll
  for (int ni = 0; ni < 4; ni++) {
    const int n = n0 + ni * 16 + l16;
    const float bv = bf2f(bias[n]);
#pragma unroll
    for (int mi = 0; mi < 4; mi++)
#pragma unroll
      for (int r = 0; r < 4; r++) {
        const int m = m0 + wave * 64 + mi * 16 + quad * 4 + r;
        out[(size_t)m * EMBED + n] = cl(acc[mi][ni][r] + bv);
      }
  }
}

// ============ flash attention: 1-wave blocks, 2 q-groups/wave ILP ===========
// (r6 version verbatim except V loads now read the fragment-ordered vt2:
// each va load is lane*16B contiguous 1KB.)
__global__ __launch_bounds__(64) void attn_kernel(
    const u16* __restrict__ kq, const u16* __restrict__ vt,
    u16* __restrict__ att) {
  __shared__ u16 Ks[2][64 * 64];
  __shared__ u32 Ps32[2][16 * 32];

  const int tid = threadIdx.x;      // 0..63, one wave
  const int quad = (tid >> 4) & 3;
  const int l16 = tid & 15;

  const int bh = blockIdx.x;             // XCD = bh % 8 (K/V L2-pinned)
  const int qt32 = 63 - (int)blockIdx.y; // heavy tiles first
  const int q0 = qt32 * 32;
  const int bq = bh >> 4;
  const int h = bh & 15;

  // q-group rows: qg = q0 + g*16 + l16
  int qg[2];
  bf16x8 bq0[2], bq1[2];
#pragma unroll
  for (int g = 0; g < 2; g++) {
    qg[g] = q0 + g * 16 + l16;
    const size_t qrow = (size_t)(bq * SEQ + qg[g]) * 2048 + EMBED + h * HS;
    bq0[g] = frag16(kq + qrow + quad * 8);
    bq1[g] = frag16(kq + qrow + 32 + quad * 8);
  }

  const u16* kb = kq + (size_t)bq * SEQ * 2048 + h * HS;        // K rows
  const u16* vb2 = vt + (size_t)(bq * 16 + h) * 32 * 4096;      // vt2 panels
  const int psw32 = (l16 & 7) << 2;  // P u32-index XOR swizzle (bits 4:2)

  // K staging: 8 passes x (64 thr x 16B) = 8KB tile. dest lane-linear
  // (p*1024 + tid*16 bytes); source colblock XOR-swizzled by row&7.
  const int sw = quad ^ (l16 & 7);           // read-side swizzle (row = *+l16)

  float lsum[2] = {0.0f, 0.0f};
  f32x4 o[2][4] = {};   // O^T C-layout: d = dc*16 + quad*4 + r, q = l16

  const int nkt = (qt32 >> 1) + 1;
#pragma unroll
  for (int p = 0; p < 8; p++) {
    const int row = p * 8 + (tid >> 3);
    const int sgc = (tid & 7) ^ (row & 7);
    glds16(kb + (size_t)row * 2048 + sgc * 8, Ks[0] + row * 64 + (tid & 7) * 8);
  }

  for (int kt = 0; kt < nkt; kt++) {
    const int k0 = kt * 64;
    __syncthreads();   // 1-wave: pure vmcnt drain (buf[kt&1] ready)
    if (kt + 1 < nkt) {
      const int kn = k0 + 64;
      u16* dst = Ks[(kt + 1) & 1];
#pragma unroll
      for (int p = 0; p < 8; p++) {
        const int row = p * 8 + (tid >> 3);
        const int sgc = (tid & 7) ^ (row & 7);
        glds16(kb + (size_t)(kn + row) * 2048 + sgc * 8, dst + row * 64 + (tid & 7) * 8);
      }
    }
    const u16* KsB = Ks[kt & 1];

    // V^T fragments from vt2 (fragment-ordered: lane*16B contiguous)
    bf16x8 va[2][4];
#pragma unroll
    for (int kc = 0; kc < 2; kc++)
#pragma unroll
      for (int dc = 0; dc < 4; dc++)
        va[kc][dc] = frag16(vb2 + (size_t)kt * 4096 +
                            ((kc * 4 + dc) * 64 + quad * 16 + l16) * 8);

    // S^T = K . Q^T : K frags read once, used by both groups
    f32x4 st[2][4] = {};
    __builtin_amdgcn_s_setprio(1);
#pragma unroll
    for (int sub = 0; sub < 4; sub++) {
      const u16* kr = KsB + (sub * 16 + l16) * 64;
      const bf16x8 ka0 = frag16(kr + sw * 8);
      const bf16x8 ka1 = frag16(kr + (sw ^ 4) * 8);
#pragma unroll
      for (int g = 0; g < 2; g++) {
        st[g][sub] = __builtin_amdgcn_mfma_f32_16x16x32_bf16(
            ka0, bq0[g], st[g][sub], 0, 0, 0);
        st[g][sub] = __builtin_amdgcn_mfma_f32_16x16x32_bf16(
            ka1, bq1[g], st[g][sub], 0, 0, 0);
      }
    }
    __builtin_amdgcn_s_setprio(0);

    // fixed-reference softmax + P pack, independent per group
    const bool diag = (kt == nkt - 1);
#pragma unroll
    for (int g = 0; g < 2; g++) {
      float p[4][4];
      if (diag) {          // last tile: mask (wave-uniform branch)
#pragma unroll
        for (int sub = 0; sub < 4; sub++)
#pragma unroll
          for (int r = 0; r < 4; r++) {
            const int key = k0 + sub * 16 + quad * 4 + r;
            const float e = __builtin_amdgcn_exp2f(st[g][sub][r] * CSCALE - MREF);
            p[sub][r] = (key <= qg[g]) ? e : 0.0f;
            lsum[g] += p[sub][r];
          }
      } else {             // fully-causal tile: no mask
#pragma unroll
        for (int sub = 0; sub < 4; sub++)
#pragma unroll
          for (int r = 0; r < 4; r++) {
            p[sub][r] = __builtin_amdgcn_exp2f(st[g][sub][r] * CSCALE - MREF);
            lsum[g] += p[sub][r];
          }
      }
      u32* pw = Ps32[g];
#pragma unroll
      for (int sub = 0; sub < 4; sub++)
#pragma unroll
        for (int rp = 0; rp < 2; rp++)
          pw[l16 * 32 + ((sub * 8 + quad * 2 + rp) ^ psw32)] =
              pk2bf(p[sub][2 * rp], p[sub][2 * rp + 1]);
    }

    // O^T += V^T . P^T : V frags shared across groups
#pragma unroll
    for (int g = 0; g < 2; g++) {
      u32* pw = Ps32[g];
#pragma unroll
      for (int kc = 0; kc < 2; kc++) {
        bf16x8 pb = frag16u(pw + l16 * 32 + ((kc * 16 + quad * 4) ^ psw32));
        __builtin_amdgcn_s_setprio(1);
#pragma unroll
        for (int dc = 0; dc < 4; dc++)
          o[g][dc] = __builtin_amdgcn_mfma_f32_16x16x32_bf16(
              va[kc][dc], pb, o[g][dc], 0, 0, 0);
        __builtin_amdgcn_s_setprio(0);
      }
    }
  }

  // row-sum reduction + epilogue per group
#pragma unroll
  for (int g = 0; g < 2; g++) {
    float ls = lsum[g];
    ls += __shfl_xor(ls, 16);
    ls += __shfl_xor(ls, 32);
    const float inv = 1.0f / ls;
    const size_t obase = (size_t)(bq * SEQ + qg[g]) * EMBED + h * HS;
#pragma unroll
    for (int dc = 0; dc < 4; dc++) {
      u16 sv[4];
#pragma unroll
      for (int r = 0; r < 4; r++) sv[r] = f2bf(cl(o[g][dc][r] * inv));
      *(u32*)(att + obase + dc * 16 + quad * 4) = (u32)sv[0] | ((u32)sv[1] << 16);
      *(u32*)(att + obase + dc * 16 + quad * 4 + 2) = (u32)sv[2] | ((u32)sv[3] << 16);
    }
  }
}

extern "C" void kernel_launch(void* const* d_in, const int* in_sizes, int n_in,
                              void* d_out, int out_size, void* d_ws,
                              size_t ws_size, hipStream_t stream) {
  const float* x       = (const float*)d_in[0];
  const float* W_atten = (const float*)d_in[1];
  const float* b_atten = (const float*)d_in[2];
  const float* W_proj  = (const float*)d_in[3];
  const float* b_proj  = (const float*)d_in[4];

  // workspace (u16 units), total 41.95 MB
  u16* wt_a = (u16*)d_ws;                         // [3072][1024]
  u16* wt_p = wt_a + (size_t)N_QKV * EMBED;       // [1024][1024]
  u16* ba   = wt_p + (size_t)EMBED * EMBED;       // [3072]
  u16* bp   = ba + N_QKV;                         // [1024]
  u16* xb   = bp + EMBED;                         // [4096][1024]
  u16* kq   = xb + (size_t)M_TOT * KDIM;          // [4096][2048]
  u16* vt   = kq + (size_t)M_TOT * 2048;          // vt2 fragment-order, 8.4MB
  u16* attb = xb;                                 // alias (xb dead after qkv GEMM)

  convert_kernel<<<(M_TOT * KDIM / 4 + 255) / 256, 256, 0, stream>>>(
      x, xb, M_TOT * KDIM / 4);
  convert_kernel<<<(N_QKV / 4 + 255) / 256, 256, 0, stream>>>(b_atten, ba, N_QKV / 4);
  convert_kernel<<<(EMBED / 4 + 255) / 256, 256, 0, stream>>>(b_proj, bp, EMBED / 4);
  transpose_conv_kernel<<<dim3(N_QKV / 32, EMBED / 32), dim3(32, 8), 0, stream>>>(
      W_atten, wt_a, EMBED, N_QKV);
  transpose_conv_kernel<<<dim3(EMBED / 32, EMBED / 32), dim3(32, 8), 0, stream>>>(
      W_proj, wt_p, EMBED, EMBED);
  gemm_qkv_kernel<<<dim3(N_QKV / 128, M_TOT / 128), 256, 0, stream>>>(
      xb, wt_a, ba, kq, vt);
  attn_kernel<<<dim3(BATCH * HEADS, SEQ / 32), 64, 0, stream>>>(kq, vt, attb);
  gemm_proj_kernel<<<dim3(EMBED / 64, M_TOT / 128), 128, 0, stream>>>(
      attb, wt_p, bp, (float*)d_out);
}